// Round 13
// baseline (1667.866 us; speedup 1.0000x reference)
//
#include <hip/hip_runtime.h>
#include <hip/hip_fp16.h>

#define HID   1024
#define NBAT  64
#define NBLK  256
#define NTHR  1024              // 16 waves -> 4 waves/SIMD (max TLP probe)
#define AROW  2056              // 2048 + 8 pad (f16 elems)
#define AVEC  257               // AROW/8
#define PLANE 65536             // f16 elems per activation plane: [256 blk][64 n][4 j]

typedef _Float16 f16;
typedef unsigned long long u64;
typedef __attribute__((ext_vector_type(8))) _Float16 f16x8;
typedef __attribute__((ext_vector_type(4))) float f32x4;

// LDS layout (bytes)
#define A_BYTES   (2 * 16 * AROW * 2)    // 131584
#define SCR_OFF   A_BYTES                // f32 [4 kg][16 rows][64 batch] = 16384
#define C_OFF     (SCR_OFF + 16384)      // f32 [2][4][64] = 2048
#define BIAS_OFF  (C_OFF + 2048)         // f32 [2][16] = 128
#define HS_OFF    (BIAS_OFF + 128)       // f16 [64][4] = 512
#define LDS_BYTES (HS_OFF + 512)         // 150656 < 160 KiB

// barrier ints (256B-spaced): leaf i: bar[64*i] i<16 |
// release flag i: bar[64*(17+i)] i<16 | xcd elect x: bar[64*(33+x)] x<8
#define BAR_INTS  (64 * 41)

#define COMPILER_FENCE() asm volatile("" ::: "memory")

__device__ __forceinline__ float sigm(float x) { return 1.f / (1.f + __expf(-x)); }
__device__ __forceinline__ float tanh_f(float x) {
  float xc = fminf(fmaxf(x, -10.f), 10.f);
  float e = __expf(2.f * xc);
  return (e - 1.f) / (e + 1.f);
}

// write-through store (coherent via MALL)
__device__ __forceinline__ void st64c(void* p, u64 v) {
  __hip_atomic_store((u64*)p, v, __ATOMIC_RELAXED, __HIP_MEMORY_SCOPE_AGENT);
}

__global__ void bar_init(int* bar) {
  int i = threadIdx.x;
  #pragma unroll
  for (int k = 0; k < 3; ++k) {
    int idx = i + k * 1024;
    if (idx < BAR_INTS) bar[idx] = 0;
  }
}

// R13 = R12 protocol (R8 flattened push-cascade barrier, inline-load GEMMs,
// shadow hh after ARRIVE, late leader inv, wave0 h+out stores, ew tid<256)
// at 1024 THREADS = 16 waves = 4 waves/SIMD -- the last TLP step.
// Wave partition: kg = wave>>2 (K-quarter), bq = wave&3 (batch quarter);
// per wave: 1 col-tile x 8 k-steps = 8 MFMA, 16 inline 8B loads. scr layout
// IDENTICAL to R12 ([4 kg][16 rows][64 cols]; bq writes cols bq*16..+16).
// Purpose: finish the TLP curve. If flat vs R12's 1553, the slot is pinned
// by the serial MALL-RT chain (store-drain + leaf RMW + release + poll +
// first-read ~ 4 RTs x ~1.2us) => structural floor; declare next round.
__global__ __launch_bounds__(NTHR, 1) void lstm_kernel(
    const float* __restrict__ x0, const float* __restrict__ h0,
    const float* __restrict__ c0, const float* __restrict__ Wih,
    const float* __restrict__ Whh, const float* __restrict__ bih,
    const float* __restrict__ bhh, const int* __restrict__ lenp,
    float* __restrict__ out, int* __restrict__ bar, f16* __restrict__ planes)
{
  extern __shared__ char smem[];
  f16*   Alds  = (f16*)smem;
  float* scr   = (float*)(smem + SCR_OFF);
  float* cS    = (float*)(smem + C_OFF);
  float* biasS = (float*)(smem + BIAS_OFF);
  f16*   hS    = (f16*)(smem + HS_OFF);     // [n][j] transpose buffer

  const int tid  = threadIdx.x;
  const int blk  = blockIdx.x;
  const int wave = tid >> 6;
  const int lane = tid & 63;
  const int quad = lane >> 4;
  const int l15  = lane & 15;
  const int kg   = wave >> 2;     // K-quarter 0..3
  const int bq   = wave & 3;      // batch quarter 0..3
  const int T    = *lenp;

  f16* l0P[2] = { planes,             planes + PLANE };
  f16* l1P[2] = { planes + 2 * PLANE, planes + 3 * PLANE };
  f16* xP     =   planes + 4 * PLANE;

  const int leafid = blk & 15;
  int* leaf  = bar + 64 * leafid;
  int* relme = bar + 64 * (17 + leafid);

  // ---- physical XCD id + one-time leader election ----
  unsigned xcc;
  asm volatile("s_getreg_b32 %0, hwreg(HW_REG_XCC_ID)" : "=s"(xcc));
  xcc &= 7;
  int is_leader = 0;
  if (tid == 0) {
    int p = __hip_atomic_fetch_add(bar + 64 * (33 + xcc), 1, __ATOMIC_RELAXED,
                                   __HIP_MEMORY_SCOPE_AGENT);
    is_leader = (p == 0);
  }

  // ---- stage weights (f32 -> f16) into LDS, 1024 threads ----
  {
    int r    = tid >> 4;          // 0..63 : l(2) x m(16) x half(2)
    int part = tid & 15;          // 16 parts x 64 f32
    int l    = r >> 5;
    int m    = (r >> 1) & 15;
    int hf   = r & 1;
    int g    = m >> 2, j = m & 3;
    size_t grow = (size_t)g * HID + blk * 4 + j;
    const float* srcW = (hf ? Whh : Wih) + ((size_t)l * 4 * HID + grow) * HID + part * 64;
    f16x8* dst = (f16x8*)(Alds + (size_t)(l * 16 + m) * AROW + hf * HID + part * 64);
    const float4* s4 = (const float4*)srcW;
    #pragma unroll 4
    for (int i = 0; i < 8; ++i) {
      float4 w0 = s4[2 * i], w1 = s4[2 * i + 1];
      f16x8 o = {(f16)w0.x, (f16)w0.y, (f16)w0.z, (f16)w0.w,
                 (f16)w1.x, (f16)w1.y, (f16)w1.z, (f16)w1.w};
      dst[i] = o;
    }
  }
  // ---- biases ----
  if (tid < 32) {
    int l = tid >> 4, m = tid & 15;
    int g = m >> 2, j = m & 3;
    size_t row = (size_t)g * HID + blk * 4 + j;
    biasS[l * 16 + m] = bih[(size_t)l * 4 * HID + row] + bhh[(size_t)l * 4 * HID + row];
  }
  // ---- c state (LDS, CU-local), original mapping gated to tid<256 ----
  if (tid < 256) {
    int j = tid >> 6, n = tid & 63;
    #pragma unroll
    for (int l = 0; l < 2; ++l)
      cS[l * 256 + j * 64 + n] =
          c0[(size_t)l * NBAT * HID + (size_t)n * HID + blk * 4 + j];
  }
  // ---- h0 -> parity-1 planes (block-contiguous, 8B/lane) ----
  if (tid < 128) {
    int l = tid >> 6, n = tid & 63;
    const float* hp = h0 + (size_t)l * NBAT * HID + (size_t)n * HID + blk * 4;
    union { u64 q; f16 h[4]; } pk;
    pk.h[0] = (f16)hp[0]; pk.h[1] = (f16)hp[1]; pk.h[2] = (f16)hp[2]; pk.h[3] = (f16)hp[3];
    st64c((l == 0 ? l0P[1] : l1P[1]) + blk * 256 + n * 4, pk.q);
  }
  // ---- x0 -> xP (each block stages its own 4-unit slot) ----
  if (tid < 64) {
    int n = tid;
    const float* xp = x0 + (size_t)n * HID + blk * 4;
    union { u64 q; f16 h[4]; } pk;
    pk.h[0] = (f16)xp[0]; pk.h[1] = (f16)xp[1]; pk.h[2] = (f16)xp[2]; pk.h[3] = (f16)xp[3];
    st64c(xP + blk * 256 + n * 4, pk.q);
  }
  // one-time safety inv (poison/stale lines) before first arrival
  if (wave == 0) asm volatile("buffer_inv sc1" ::: "memory");

  // ---- split grid barrier (R8, proven): flattened push cascade ----
  int epoch = 1;

  #define ARRIVE()                                                              \
    do {                                                                        \
      asm volatile("s_waitcnt vmcnt(0)" ::: "memory");                          \
      if (tid == 0) {                                                           \
        int prev = __hip_atomic_fetch_add(leaf, 1, __ATOMIC_RELAXED,            \
                                          __HIP_MEMORY_SCOPE_AGENT);            \
        if (prev == 16 * epoch - 1) {                                           \
          _Pragma("unroll")                                                     \
          for (int i_ = 0; i_ < 16; ++i_)                                       \
            (void)__hip_atomic_fetch_add(bar + 64 * (17 + i_), 1,               \
                                         __ATOMIC_RELAXED,                      \
                                         __HIP_MEMORY_SCOPE_AGENT);             \
        }                                                                       \
      }                                                                         \
    } while (0)

  #define WAIT_REL()                                                            \
    do {                                                                        \
      if (tid == 0) {                                                           \
        while (__hip_atomic_fetch_add(relme, 0, __ATOMIC_RELAXED,               \
                                      __HIP_MEMORY_SCOPE_AGENT) < 16 * epoch)   \
          __builtin_amdgcn_s_sleep(1);                                          \
      }                                                                         \
      epoch++;                                                                  \
      __syncthreads();                                                          \
      COMPILER_FENCE();                                                         \
    } while (0)

  // initial barrier: every wave drains its own staging stores, converges,
  // then tid0 arrives
  asm volatile("s_waitcnt vmcnt(0)" ::: "memory");
  __syncthreads();
  ARRIVE();
  WAIT_REL();

  const f16x8* Av = (const f16x8*)Alds;
  const f32x4 fz = {0.f, 0.f, 0.f, 0.f};
  f32x4 a0;

  // K=256 x 16-batch GEMM slice: kg selects the K-quarter, bq the batch
  // quarter. 8 MFMA, 16 inline 8B loads per wave.
  auto gemmSlice = [&](const f16* psrc, int aoffbase) {
    int aoff = aoffbase + kg * 32 + quad;
    const f16* p0 = psrc + (kg * 64 + quad * 2) * 256 + l15 * 4 + bq * 64;
    #pragma unroll
    for (int kk = 0; kk < 8; ++kk) {
      f16x8 af = Av[aoff + kk * 4];
      const f16* k0 = p0 + kk * 2048;
      union { u64 q[2]; f16x8 v; } b0;
      b0.q[0] = *(const u64*)(k0 +   0); b0.q[1] = *(const u64*)(k0 + 256);
      a0 = __builtin_amdgcn_mfma_f32_16x16x32_f16(af, b0.v, a0, 0, 0, 0);
    }
  };

  // ---- prologue: hh(t=0,l=0) from the initial h0 plane (parity 1) ----
  a0 = fz;
  gemmSlice(l0P[1], (0 * 16 + l15) * AVEC + 128);

  const int NP = 2 * T;
  #pragma unroll 1
  for (int p = 0; p < NP; ++p) {
    const int L = p & 1, t = p >> 1, wp = t & 1, rp = wp ^ 1;
    if (p) WAIT_REL();

    // ---- ih-GEMM(p): operand written at slot p-1, visible per WAIT ----
    const f16* pIh = L ? l0P[wp] : (t ? l1P[rp] : xP);
    gemmSlice(pIh, (L * 16 + l15) * AVEC);

    // ---- partials (hh(p)+ih(p)) to LDS scratch ----
    {
      float* sc = scr + kg * 1024;
      #pragma unroll
      for (int r = 0; r < 4; ++r) {
        int base = (quad * 4 + r) * 64 + bq * 16 + l15;
        sc[base] = a0[r];
      }
    }
    __syncthreads();

    // ---- elementwise: thread = (unit j, batch n), tid<256 ----
    if (tid < 256) {
      int j = tid >> 6, n = tid & 63;
      float gate[4];
      #pragma unroll
      for (int g = 0; g < 4; ++g) {
        int b0i = (g * 4 + j) * 64 + n;
        gate[g] = scr[b0i] + scr[1024 + b0i] + scr[2048 + b0i] + scr[3072 + b0i]
                + biasS[L * 16 + g * 4 + j];
      }
      float cold = cS[L * 256 + j * 64 + n];
      float cn = sigm(gate[1]) * cold + sigm(gate[0]) * tanh_f(gate[2]);
      float hn = sigm(gate[3]) * tanh_f(cn);
      cS[L * 256 + j * 64 + n] = cn;
      hS[n * 4 + j] = (f16)hn;
    }
    __syncthreads();

    // ---- h store: ONE contiguous 512B chunk per block (+ out on L==1) ----
    if (tid < 64) {
      int n = tid;
      union { u64 q; f16 h[4]; } pk;
      pk.q = *(const u64*)(hS + n * 4);
      st64c((L == 0 ? l0P[wp] : l1P[wp]) + blk * 256 + n * 4, pk.q);
      if (L == 1) {
        union { u64 q; float f[2]; } o0, o1;
        o0.f[0] = (float)pk.h[0]; o0.f[1] = (float)pk.h[1];
        o1.f[0] = (float)pk.h[2]; o1.f[1] = (float)pk.h[3];
        float* op = out + (size_t)n * T * HID + (size_t)t * HID + blk * 4;
        st64c(op, o0.q);
        st64c(op + 2, o1.q);
      }
    }

    if (p < NP - 1) {
      // ARRIVE drains wave0's stores (tid0 is wave0), fires arrival (and,
      // for a leaf finisher, the 16 one-way release adds). Shadow =
      // hh(p+1): operand visible since WAIT(p-1); SAME plane ih just
      // read -> L2-hot.
      ARRIVE();
      const f16* pSh = L ? l0P[wp] : l1P[rp];
      a0 = fz;
      gemmSlice(pSh, ((L ^ 1) * 16 + l15) * AVEC + 128);
      // leader inv AFTER shadow reads: clears stale lines for next slot's
      // plane without evicting this slot's hot lines
      if (is_leader) asm volatile("buffer_inv sc1" ::: "memory");
    } else {
      asm volatile("s_waitcnt vmcnt(0)" ::: "memory");
    }
  }
}

extern "C" void kernel_launch(void* const* d_in, const int* in_sizes, int n_in,
                              void* d_out, int out_size, void* d_ws, size_t ws_size,
                              hipStream_t stream) {
  const float* x0  = (const float*)d_in[0];
  const float* h0  = (const float*)d_in[1];
  const float* c0  = (const float*)d_in[2];
  const float* Wih = (const float*)d_in[3];
  const float* Whh = (const float*)d_in[4];
  const float* bih = (const float*)d_in[5];
  const float* bhh = (const float*)d_in[6];
  const int* lenp  = (const int*)d_in[7];
  float* out = (float*)d_out;

  int* bar    = (int*)d_ws;
  f16* planes = (f16*)((char*)d_ws + 16384);   // 5 planes x 128 KB

  hipFuncSetAttribute((const void*)lstm_kernel,
                      hipFuncAttributeMaxDynamicSharedMemorySize, LDS_BYTES);

  bar_init<<<1, 1024, 0, stream>>>(bar);

  void* args[] = {&x0, &h0, &c0, &Wih, &Whh, &bih, &bhh, &lenp, &out, &bar, &planes};
  hipLaunchCooperativeKernel((void*)lstm_kernel, dim3(NBLK), dim3(NTHR),
                             args, LDS_BYTES, stream);
}

// Round 14
// 1623.138 us; speedup vs baseline: 1.0276x; 1.0276x over previous
//
#include <hip/hip_runtime.h>
#include <hip/hip_fp16.h>

#define HID   1024
#define NBAT  64
#define NBLK  256
#define NTHR  512               // 8 waves -> 2 waves/SIMD (TLP optimum, R12/R13)
#define AROW  2056              // 2048 + 8 pad (f16 elems)
#define AVEC  257               // AROW/8
#define PLANE 65536             // f16 elems per activation plane: [256 blk][64 n][4 j]

typedef _Float16 f16;
typedef unsigned long long u64;
typedef __attribute__((ext_vector_type(8))) _Float16 f16x8;
typedef __attribute__((ext_vector_type(4))) float f32x4;

// LDS layout (bytes)
#define A_BYTES   (2 * 16 * AROW * 2)    // 131584
#define SCR_OFF   A_BYTES                // f32 [4 kg][16 rows][64 batch] = 16384
#define C_OFF     (SCR_OFF + 16384)      // f32 [2][4][64] = 2048
#define BIAS_OFF  (C_OFF + 2048)         // f32 [2][16] = 128
#define HS_OFF    (BIAS_OFF + 128)       // f16 [64][4] = 512
#define LDS_BYTES (HS_OFF + 512)         // 150656 < 160 KiB

// barrier ints (256B-spaced): leaf i: bar[64*i] i<16 |
// release flag i: bar[64*(17+i)] i<16 | xcd elect x: bar[64*(33+x)] x<8
#define BAR_INTS  (64 * 41)

#define COMPILER_FENCE() asm volatile("" ::: "memory")

__device__ __forceinline__ float sigm(float x) { return 1.f / (1.f + __expf(-x)); }
__device__ __forceinline__ float tanh_f(float x) {
  float xc = fminf(fmaxf(x, -10.f), 10.f);
  float e = __expf(2.f * xc);
  return (e - 1.f) / (e + 1.f);
}

// write-through store (coherent via MALL)
__device__ __forceinline__ void st64c(void* p, u64 v) {
  __hip_atomic_store((u64*)p, v, __ATOMIC_RELAXED, __HIP_MEMORY_SCOPE_AGENT);
}

__global__ void bar_init(int* bar) {
  int i = threadIdx.x;
  #pragma unroll
  for (int k = 0; k < 3; ++k) {
    int idx = i + k * 1024;
    if (idx < BAR_INTS) bar[idx] = 0;
  }
}

// R14 = R12 verbatim (session best, 1553us; 27% faster than the 2120us
// session-start baseline). Structure: R8 flattened push-cascade grid
// barrier (one-way leaf arrival; leaf finisher adds +1 to all 16 release
// flags; pollers wait relme >= 16*epoch), inline-load GEMMs (no operand-
// register carry across sync points -- R3-R6 lesson), shadow hh-GEMM after
// ARRIVE on the L2-hot plane, late leader buffer_inv, wave0 h+out stores.
// 8 waves = 2 waves/SIMD: the TLP optimum (4w=1602, 8w=1553, 16w=1612).
// Structural ceiling (R8-R13 evidence): the slot is pinned by the serial
// cross-die MALL round-trip chain (store-drain + arrival RMW + release +
// poll-detect + first-read ~ 4-5 x ~1.1us); barrier depth, GEMM issue
// structure, poll discipline, and TLP beyond 2/SIMD are all within +-4%.
__global__ __launch_bounds__(NTHR, 1) void lstm_kernel(
    const float* __restrict__ x0, const float* __restrict__ h0,
    const float* __restrict__ c0, const float* __restrict__ Wih,
    const float* __restrict__ Whh, const float* __restrict__ bih,
    const float* __restrict__ bhh, const int* __restrict__ lenp,
    float* __restrict__ out, int* __restrict__ bar, f16* __restrict__ planes)
{
  extern __shared__ char smem[];
  f16*   Alds  = (f16*)smem;
  float* scr   = (float*)(smem + SCR_OFF);
  float* cS    = (float*)(smem + C_OFF);
  float* biasS = (float*)(smem + BIAS_OFF);
  f16*   hS    = (f16*)(smem + HS_OFF);     // [n][j] transpose buffer

  const int tid  = threadIdx.x;
  const int blk  = blockIdx.x;
  const int wave = tid >> 6;
  const int lane = tid & 63;
  const int quad = lane >> 4;
  const int l15  = lane & 15;
  const int kg   = wave >> 1;     // K-quarter 0..3
  const int half = wave & 1;      // batch half 0..1
  const int T    = *lenp;

  f16* l0P[2] = { planes,             planes + PLANE };
  f16* l1P[2] = { planes + 2 * PLANE, planes + 3 * PLANE };
  f16* xP     =   planes + 4 * PLANE;

  const int leafid = blk & 15;
  int* leaf  = bar + 64 * leafid;
  int* relme = bar + 64 * (17 + leafid);

  // ---- physical XCD id + one-time leader election ----
  unsigned xcc;
  asm volatile("s_getreg_b32 %0, hwreg(HW_REG_XCC_ID)" : "=s"(xcc));
  xcc &= 7;
  int is_leader = 0;
  if (tid == 0) {
    int p = __hip_atomic_fetch_add(bar + 64 * (33 + xcc), 1, __ATOMIC_RELAXED,
                                   __HIP_MEMORY_SCOPE_AGENT);
    is_leader = (p == 0);
  }

  // ---- stage weights (f32 -> f16) into LDS, 512 threads ----
  {
    int r    = tid >> 3;          // 0..63 : l(2) x m(16) x half(2)
    int part = tid & 7;           // 8 parts x 128 f32
    int l    = r >> 5;
    int m    = (r >> 1) & 15;
    int hf   = r & 1;
    int g    = m >> 2, j = m & 3;
    size_t grow = (size_t)g * HID + blk * 4 + j;
    const float* srcW = (hf ? Whh : Wih) + ((size_t)l * 4 * HID + grow) * HID + part * 128;
    f16x8* dst = (f16x8*)(Alds + (size_t)(l * 16 + m) * AROW + hf * HID + part * 128);
    const float4* s4 = (const float4*)srcW;
    #pragma unroll 4
    for (int i = 0; i < 16; ++i) {
      float4 w0 = s4[2 * i], w1 = s4[2 * i + 1];
      f16x8 o = {(f16)w0.x, (f16)w0.y, (f16)w0.z, (f16)w0.w,
                 (f16)w1.x, (f16)w1.y, (f16)w1.z, (f16)w1.w};
      dst[i] = o;
    }
  }
  // ---- biases ----
  if (tid < 32) {
    int l = tid >> 4, m = tid & 15;
    int g = m >> 2, j = m & 3;
    size_t row = (size_t)g * HID + blk * 4 + j;
    biasS[l * 16 + m] = bih[(size_t)l * 4 * HID + row] + bhh[(size_t)l * 4 * HID + row];
  }
  // ---- c state (LDS, CU-local), original mapping gated to tid<256 ----
  if (tid < 256) {
    int j = tid >> 6, n = tid & 63;
    #pragma unroll
    for (int l = 0; l < 2; ++l)
      cS[l * 256 + j * 64 + n] =
          c0[(size_t)l * NBAT * HID + (size_t)n * HID + blk * 4 + j];
  }
  // ---- h0 -> parity-1 planes (block-contiguous, 8B/lane) ----
  if (tid < 128) {
    int l = tid >> 6, n = tid & 63;
    const float* hp = h0 + (size_t)l * NBAT * HID + (size_t)n * HID + blk * 4;
    union { u64 q; f16 h[4]; } pk;
    pk.h[0] = (f16)hp[0]; pk.h[1] = (f16)hp[1]; pk.h[2] = (f16)hp[2]; pk.h[3] = (f16)hp[3];
    st64c((l == 0 ? l0P[1] : l1P[1]) + blk * 256 + n * 4, pk.q);
  }
  // ---- x0 -> xP (each block stages its own 4-unit slot) ----
  if (tid < 64) {
    int n = tid;
    const float* xp = x0 + (size_t)n * HID + blk * 4;
    union { u64 q; f16 h[4]; } pk;
    pk.h[0] = (f16)xp[0]; pk.h[1] = (f16)xp[1]; pk.h[2] = (f16)xp[2]; pk.h[3] = (f16)xp[3];
    st64c(xP + blk * 256 + n * 4, pk.q);
  }
  // one-time safety inv (poison/stale lines) before first arrival
  if (wave == 0) asm volatile("buffer_inv sc1" ::: "memory");

  // ---- split grid barrier (R8, proven): flattened push cascade ----
  int epoch = 1;

  #define ARRIVE()                                                              \
    do {                                                                        \
      asm volatile("s_waitcnt vmcnt(0)" ::: "memory");                          \
      if (tid == 0) {                                                           \
        int prev = __hip_atomic_fetch_add(leaf, 1, __ATOMIC_RELAXED,            \
                                          __HIP_MEMORY_SCOPE_AGENT);            \
        if (prev == 16 * epoch - 1) {                                           \
          _Pragma("unroll")                                                     \
          for (int i_ = 0; i_ < 16; ++i_)                                       \
            (void)__hip_atomic_fetch_add(bar + 64 * (17 + i_), 1,               \
                                         __ATOMIC_RELAXED,                      \
                                         __HIP_MEMORY_SCOPE_AGENT);             \
        }                                                                       \
      }                                                                         \
    } while (0)

  #define WAIT_REL()                                                            \
    do {                                                                        \
      if (tid == 0) {                                                           \
        while (__hip_atomic_fetch_add(relme, 0, __ATOMIC_RELAXED,               \
                                      __HIP_MEMORY_SCOPE_AGENT) < 16 * epoch)   \
          __builtin_amdgcn_s_sleep(1);                                          \
      }                                                                         \
      epoch++;                                                                  \
      __syncthreads();                                                          \
      COMPILER_FENCE();                                                         \
    } while (0)

  // initial barrier: every wave drains its own staging stores, converges,
  // then tid0 arrives
  asm volatile("s_waitcnt vmcnt(0)" ::: "memory");
  __syncthreads();
  ARRIVE();
  WAIT_REL();

  const f16x8* Av = (const f16x8*)Alds;
  const f32x4 fz = {0.f, 0.f, 0.f, 0.f};
  f32x4 a0, a1;

  // K=256 x 32-batch GEMM slice for this wave: kg selects the K-quarter,
  // half selects the batch half. 16 MFMA, 32 inline 8B loads.
  auto gemmSlice = [&](const f16* psrc, int aoffbase) {
    int aoff = aoffbase + kg * 32 + quad;
    const f16* p0 = psrc + (kg * 64 + quad * 2) * 256 + l15 * 4 + half * 128;
    #pragma unroll
    for (int kk = 0; kk < 8; ++kk) {
      f16x8 af = Av[aoff + kk * 4];
      const f16* k0 = p0 + kk * 2048;
      union { u64 q[2]; f16x8 v; } b0, b1;
      b0.q[0] = *(const u64*)(k0 +   0); b0.q[1] = *(const u64*)(k0 + 256);
      b1.q[0] = *(const u64*)(k0 +  64); b1.q[1] = *(const u64*)(k0 + 320);
      a0 = __builtin_amdgcn_mfma_f32_16x16x32_f16(af, b0.v, a0, 0, 0, 0);
      a1 = __builtin_amdgcn_mfma_f32_16x16x32_f16(af, b1.v, a1, 0, 0, 0);
    }
  };

  // ---- prologue: hh(t=0,l=0) from the initial h0 plane (parity 1) ----
  a0 = fz; a1 = fz;
  gemmSlice(l0P[1], (0 * 16 + l15) * AVEC + 128);

  const int NP = 2 * T;
  #pragma unroll 1
  for (int p = 0; p < NP; ++p) {
    const int L = p & 1, t = p >> 1, wp = t & 1, rp = wp ^ 1;
    if (p) WAIT_REL();

    // ---- ih-GEMM(p): operand written at slot p-1, visible per WAIT ----
    const f16* pIh = L ? l0P[wp] : (t ? l1P[rp] : xP);
    gemmSlice(pIh, (L * 16 + l15) * AVEC);

    // ---- partials (hh(p)+ih(p)) to LDS scratch ----
    {
      float* sc = scr + kg * 1024;
      #pragma unroll
      for (int r = 0; r < 4; ++r) {
        int base = (quad * 4 + r) * 64 + l15 + half * 32;
        sc[base +  0] = a0[r];
        sc[base + 16] = a1[r];
      }
    }
    __syncthreads();

    // ---- elementwise: thread = (unit j, batch n), tid<256 ----
    if (tid < 256) {
      int j = tid >> 6, n = tid & 63;
      float gate[4];
      #pragma unroll
      for (int g = 0; g < 4; ++g) {
        int b0i = (g * 4 + j) * 64 + n;
        gate[g] = scr[b0i] + scr[1024 + b0i] + scr[2048 + b0i] + scr[3072 + b0i]
                + biasS[L * 16 + g * 4 + j];
      }
      float cold = cS[L * 256 + j * 64 + n];
      float cn = sigm(gate[1]) * cold + sigm(gate[0]) * tanh_f(gate[2]);
      float hn = sigm(gate[3]) * tanh_f(cn);
      cS[L * 256 + j * 64 + n] = cn;
      hS[n * 4 + j] = (f16)hn;
    }
    __syncthreads();

    // ---- h store: ONE contiguous 512B chunk per block (+ out on L==1) ----
    if (tid < 64) {
      int n = tid;
      union { u64 q; f16 h[4]; } pk;
      pk.q = *(const u64*)(hS + n * 4);
      st64c((L == 0 ? l0P[wp] : l1P[wp]) + blk * 256 + n * 4, pk.q);
      if (L == 1) {
        union { u64 q; float f[2]; } o0, o1;
        o0.f[0] = (float)pk.h[0]; o0.f[1] = (float)pk.h[1];
        o1.f[0] = (float)pk.h[2]; o1.f[1] = (float)pk.h[3];
        float* op = out + (size_t)n * T * HID + (size_t)t * HID + blk * 4;
        st64c(op, o0.q);
        st64c(op + 2, o1.q);
      }
    }

    if (p < NP - 1) {
      // ARRIVE drains wave0's stores (tid0 is wave0), fires arrival (and,
      // for a leaf finisher, the 16 one-way release adds). Shadow =
      // hh(p+1): operand visible since WAIT(p-1); SAME plane ih just
      // read -> L2-hot.
      ARRIVE();
      const f16* pSh = L ? l0P[wp] : l1P[rp];
      a0 = fz; a1 = fz;
      gemmSlice(pSh, ((L ^ 1) * 16 + l15) * AVEC + 128);
      // leader inv AFTER shadow reads: clears stale lines for next slot's
      // plane without evicting this slot's hot lines
      if (is_leader) asm volatile("buffer_inv sc1" ::: "memory");
    } else {
      asm volatile("s_waitcnt vmcnt(0)" ::: "memory");
    }
  }
}

extern "C" void kernel_launch(void* const* d_in, const int* in_sizes, int n_in,
                              void* d_out, int out_size, void* d_ws, size_t ws_size,
                              hipStream_t stream) {
  const float* x0  = (const float*)d_in[0];
  const float* h0  = (const float*)d_in[1];
  const float* c0  = (const float*)d_in[2];
  const float* Wih = (const float*)d_in[3];
  const float* Whh = (const float*)d_in[4];
  const float* bih = (const float*)d_in[5];
  const float* bhh = (const float*)d_in[6];
  const int* lenp  = (const int*)d_in[7];
  float* out = (float*)d_out;

  int* bar    = (int*)d_ws;
  f16* planes = (f16*)((char*)d_ws + 16384);   // 5 planes x 128 KB

  hipFuncSetAttribute((const void*)lstm_kernel,
                      hipFuncAttributeMaxDynamicSharedMemorySize, LDS_BYTES);

  bar_init<<<1, 1024, 0, stream>>>(bar);

  void* args[] = {&x0, &h0, &c0, &Wih, &Whh, &bih, &bhh, &lenp, &out, &bar, &planes};
  hipLaunchCooperativeKernel((void*)lstm_kernel, dim3(NBLK), dim3(NTHR),
                             args, LDS_BYTES, stream);
}